// Round 3
// baseline (583.672 us; speedup 1.0000x reference)
//
#include <hip/hip_runtime.h>
#include <hip/hip_bf16.h>

// Problem constants (match reference)
constexpr int N  = 50000;    // nodes
constexpr int E  = 1600000;  // edges
constexpr int CH = 128;      // in/out channels

// Workspace layout (bytes). h is now bf16 but we keep the fp32-sized slot
// reserved (layout unchanged from R2, REQUIRED unchanged).
constexpr size_t H_OFF     = 0;                       // h (bf16) [N*CH]
constexpr size_t H_BYTES   = (size_t)N * CH * 4;      // reserved 25,600,000
constexpr size_t CSR_OFF   = H_OFF + H_BYTES;         // csr src ids [E] i32
constexpr size_t CSR_BYTES = (size_t)E * 4;           // 6,400,000
constexpr size_t DEG_BYTES = 200192;                  // 50048 ints
constexpr size_t DEG_OFF   = CSR_OFF + CSR_BYTES;     // degree   [N] i32
constexpr size_t OFFS_OFF  = DEG_OFF + DEG_BYTES;     // offsets  [N] i32
constexpr size_t CUR_OFF   = OFFS_OFF + DEG_BYTES;    // cursors  [N] i32
constexpr size_t REQUIRED  = CUR_OFF + DEG_BYTES + 256;

// float -> bf16 (round to nearest even; inputs are finite)
static __device__ __forceinline__ ushort f2bf(float f) {
    unsigned u = __float_as_uint(f);
    return (ushort)((u + 0x7fffu + ((u >> 16) & 1u)) >> 16);
}

// ---------------- GEMM: h = x @ W^T + b, stored bf16 ----------------
// 16 x-rows per block, 256 threads. W staged in LDS in two 64-row halves
// (LDS = (16+64)*129*4 = 41,280 B). Stride 129 breaks bank-conflict pattern.
__global__ __launch_bounds__(256) void gemm_bias(const float* __restrict__ x,
                                                 const float* __restrict__ W,
                                                 const float* __restrict__ b,
                                                 ushort* __restrict__ h) {
    __shared__ float xs[16 * 129];
    __shared__ float ws[64 * 129];
    const int t  = threadIdx.x;
    const int r0 = blockIdx.x * 16;

    // Stage x tile: 16*128 floats = 512 float4, 2 per thread
    {
        const float4* x4 = (const float4*)(x + (size_t)r0 * CH);
        for (int i = 0; i < 2; i++) {
            int idx = t + i * 256;
            float4 v = x4[idx];
            int r = idx >> 5;
            int d = (idx & 31) * 4;
            float* p = &xs[r * 129 + d];
            p[0] = v.x; p[1] = v.y; p[2] = v.z; p[3] = v.w;
        }
    }

    const int tc = (t & 15) * 4;   // 4 output cols within 64-col half
    const int tr = t >> 4;         // row 0..15

    for (int half = 0; half < 2; half++) {
        __syncthreads();
        const float4* W4 = (const float4*)(W + (size_t)half * 64 * CH);
        for (int i = 0; i < 8; i++) {
            int idx = t + i * 256;
            float4 v = W4[idx];
            int o = idx >> 5;
            int d = (idx & 31) * 4;
            float* p = &ws[o * 129 + d];
            p[0] = v.x; p[1] = v.y; p[2] = v.z; p[3] = v.w;
        }
        __syncthreads();

        float acc0 = 0.f, acc1 = 0.f, acc2 = 0.f, acc3 = 0.f;
#pragma unroll 4
        for (int k = 0; k < 128; k++) {
            float xv = xs[tr * 129 + k];
            acc0 += xv * ws[(tc + 0) * 129 + k];
            acc1 += xv * ws[(tc + 1) * 129 + k];
            acc2 += xv * ws[(tc + 2) * 129 + k];
            acc3 += xv * ws[(tc + 3) * 129 + k];
        }
        int col = half * 64 + tc;
        ushort4 r;
        r.x = f2bf(acc0 + b[col + 0]);
        r.y = f2bf(acc1 + b[col + 1]);
        r.z = f2bf(acc2 + b[col + 2]);
        r.w = f2bf(acc3 + b[col + 3]);
        // 50000 % 16 == 0: no row guard. 8-byte aligned (col%4==0).
        *(ushort4*)(h + (size_t)(r0 + tr) * CH + col) = r;
    }
}

// ---------------- degree histogram (4 edges/thread, int4) ----------------
__global__ void hist_kernel(const int* __restrict__ ei, int* __restrict__ deg) {
    int i = blockIdx.x * blockDim.x + threadIdx.x;   // i-th edge quad
    if (i < E / 4) {
        int4 d4 = ((const int4*)ei)[i];   // row 0 = dst
        atomicAdd(&deg[d4.x], 1);
        atomicAdd(&deg[d4.y], 1);
        atomicAdd(&deg[d4.z], 1);
        atomicAdd(&deg[d4.w], 1);
    }
}

// ---------------- fused exclusive scan (one block) ----------------
// 1024 threads * 49 contiguous elems = 50176 >= N. Writes offs and cur.
__global__ __launch_bounds__(1024) void scan_all(const int* __restrict__ deg,
                                                 int* __restrict__ offs,
                                                 int* __restrict__ cur) {
    __shared__ int s[1024];
    const int t = threadIdx.x;
    const int base = t * 49;
    int sum = 0;
#pragma unroll
    for (int i = 0; i < 49; i++) {
        int j = base + i;
        if (j < N) sum += deg[j];
    }
    s[t] = sum;
    __syncthreads();
    for (int o = 1; o < 1024; o <<= 1) {
        int tmp = (t >= o) ? s[t - o] : 0;
        __syncthreads();
        s[t] += tmp;
        __syncthreads();
    }
    int run = s[t] - sum;   // exclusive prefix of this thread's chunk
#pragma unroll
    for (int i = 0; i < 49; i++) {
        int j = base + i;
        if (j < N) {
            offs[j] = run;
            cur[j]  = run;
            run += deg[j];
        }
    }
}

// ---------------- scatter edges into CSR (4 edges/thread) ----------------
__global__ void scatter_kernel(const int* __restrict__ ei,
                               int* __restrict__ cur, int* __restrict__ csr) {
    int i = blockIdx.x * blockDim.x + threadIdx.x;
    if (i < E / 4) {
        int4 d4 = ((const int4*)ei)[i];
        int4 s4 = ((const int4*)(ei + E))[i];
        csr[atomicAdd(&cur[d4.x], 1)] = s4.x;
        csr[atomicAdd(&cur[d4.y], 1)] = s4.y;
        csr[atomicAdd(&cur[d4.z], 1)] = s4.z;
        csr[atomicAdd(&cur[d4.w], 1)] = s4.w;
    }
}

// ---------------- pull aggregation over bf16 h ----------------
// One wave per node; each lane owns 2 channels (one 4 B load per edge,
// wave reads the full 256 B row contiguously).
__global__ __launch_bounds__(64) void agg_bf16(const ushort* __restrict__ h,
                                               const int* __restrict__ offs,
                                               const int* __restrict__ deg,
                                               const int* __restrict__ csr,
                                               float* __restrict__ out) {
    const int n  = blockIdx.x;
    const int c2 = threadIdx.x;        // channel pair 0..63
    const int st = offs[n];
    const int cnt = deg[n];
    float a0 = 0.f, a1 = 0.f;
    for (int i = 0; i < cnt; i++) {
        int s = csr[st + i];
        unsigned v = *(const unsigned*)(h + (size_t)s * CH + c2 * 2);
        a0 += __uint_as_float(v << 16);           // low ushort = even channel
        a1 += __uint_as_float(v & 0xffff0000u);   // high ushort = odd channel
    }
    float2 r = make_float2(a0, a1);
    *(float2*)(out + (size_t)n * CH + c2 * 2) = r;   // deg==0 -> zeros
}

// ---------------- fallback: direct atomic scatter (needs only h in ws) ----------------
__global__ void atomic_agg(const ushort* __restrict__ h, const int* __restrict__ ei,
                           float* __restrict__ out) {
    int tid = blockIdx.x * blockDim.x + threadIdx.x;
    int e  = tid >> 5;          // 32 threads per edge, 4 channels each
    int cg = (tid & 31) * 4;
    if (e < E) {
        int d = ei[e];
        int s = ei[E + e];
        ushort4 v = *(const ushort4*)(h + (size_t)s * CH + cg);
        float* o = out + (size_t)d * CH + cg;
        atomicAdd(o + 0, __uint_as_float((unsigned)v.x << 16));
        atomicAdd(o + 1, __uint_as_float((unsigned)v.y << 16));
        atomicAdd(o + 2, __uint_as_float((unsigned)v.z << 16));
        atomicAdd(o + 3, __uint_as_float((unsigned)v.w << 16));
    }
}

extern "C" void kernel_launch(void* const* d_in, const int* in_sizes, int n_in,
                              void* d_out, int out_size, void* d_ws, size_t ws_size,
                              hipStream_t stream) {
    const float* x  = (const float*)d_in[0];
    const int*   ei = (const int*)d_in[1];   // int32 per harness contract
    const float* W  = (const float*)d_in[2];
    const float* b  = (const float*)d_in[3];
    float* out = (float*)d_out;

    char* ws = (char*)d_ws;
    ushort* h = (ushort*)(ws + H_OFF);

    gemm_bias<<<N / 16, 256, 0, stream>>>(x, W, b, h);

    if (ws_size >= REQUIRED) {
        int* csr  = (int*)(ws + CSR_OFF);
        int* deg  = (int*)(ws + DEG_OFF);
        int* offs = (int*)(ws + OFFS_OFF);
        int* cur  = (int*)(ws + CUR_OFF);

        hipMemsetAsync(deg, 0, DEG_BYTES, stream);  // ws re-poisoned every call
        hist_kernel<<<(E / 4 + 255) / 256, 256, 0, stream>>>(ei, deg);
        scan_all<<<1, 1024, 0, stream>>>(deg, offs, cur);
        scatter_kernel<<<(E / 4 + 255) / 256, 256, 0, stream>>>(ei, cur, csr);
        agg_bf16<<<N, 64, 0, stream>>>(h, offs, deg, csr, out);
    } else {
        hipMemsetAsync(out, 0, (size_t)out_size * sizeof(float), stream);
        int total = E * 32;
        atomic_agg<<<(total + 255) / 256, 256, 0, stream>>>(h, ei, out);
    }
}

// Round 4
// 256.052 us; speedup vs baseline: 2.2795x; 2.2795x over previous
//
#include <hip/hip_runtime.h>

// Problem constants
constexpr int N  = 50000;    // nodes
constexpr int E  = 1600000;  // edges
constexpr int CH = 128;      // channels

// Bucketed CSR build parameters
constexpr int NB   = 196;        // buckets of 256 nodes (50000/256 -> 196)
constexpr int PBLK = 256;        // partition blocks
constexpr int EPB  = E / PBLK;   // 6250 edges per partition block (exact)

// Workspace layout (bytes, all 256-aligned)
constexpr size_t H_OFF     = 0;                         // h bf16 [N*CH]
constexpr size_t H_SZ      = (size_t)N * CH * 2;        // 12,800,000
constexpr size_t WBF_OFF   = H_OFF + H_SZ;              // W bf16 [CH*CH]
constexpr size_t WBF_SZ    = (size_t)CH * CH * 2;       // 32,768
constexpr size_t PAIRS_OFF = WBF_OFF + WBF_SZ;          // (dst,src) pairs [E] int2
constexpr size_t PAIRS_SZ  = (size_t)E * 8;             // 12,800,000
constexpr size_t CSR_OFF   = PAIRS_OFF + PAIRS_SZ;      // csr src ids [E] i32
constexpr size_t CSR_SZ    = (size_t)E * 4;             // 6,400,000
constexpr size_t CNT_OFF   = CSR_OFF + CSR_SZ;          // counts [NB][PBLK] i32
constexpr size_t CNT_SZ    = (size_t)NB * PBLK * 4;     // 200,704
constexpr size_t DEG_OFF   = CNT_OFF + CNT_SZ;          // degree [N] i32
constexpr size_t DEG_SZ    = 200704;
constexpr size_t OFFS_OFF  = DEG_OFF + DEG_SZ;          // offsets [N] i32
constexpr size_t OFFS_SZ   = 200704;
constexpr size_t BASE_OFF  = OFFS_OFF + OFFS_SZ;        // bucket bases [NB+1] i32
constexpr size_t BASE_SZ   = 1024;
constexpr size_t REQUIRED  = BASE_OFF + BASE_SZ;        // ~32.64 MB
constexpr size_t FB_REQUIRED = PAIRS_OFF;               // fallback: h + W_bf only

// float -> bf16 round-to-nearest-even (finite inputs)
static __device__ __forceinline__ ushort f2bf(float f) {
    unsigned u = __float_as_uint(f);
    return (ushort)((u + 0x7fffu + ((u >> 16) & 1u)) >> 16);
}

typedef __attribute__((ext_vector_type(8))) short bf16x8;
typedef __attribute__((ext_vector_type(4))) float f32x4;

// ---------------- W fp32 -> bf16 ----------------
__global__ void convert_w(const float* __restrict__ W, ushort* __restrict__ wbf) {
    int i = blockIdx.x * 256 + threadIdx.x;   // 64 blocks x 256 = 16384
    wbf[i] = f2bf(W[i]);
}

// ---------------- GEMM via MFMA: h = bf16(x @ W^T + b) ----------------
// Block = 4 waves, covers 16 rows x 128 cols. Wave w: cols [w*32, w*32+32).
// A-frag: lane holds x[r0+(lane&15)][kc + q*8 + j], q=lane>>4, j=0..7 (fp32
// loaded 32B/lane, converted in-register). B-frag: lane holds
// W[c0+ct*16+(lane&15)][kc + q*8 + j] (bf16, one 16B load). D: col=lane&15,
// row=q*4+reg (guide-verified m89/m91). No LDS.
__global__ __launch_bounds__(256) void gemm_mfma(const float* __restrict__ x,
                                                 const ushort* __restrict__ wbf,
                                                 const float* __restrict__ bias,
                                                 ushort* __restrict__ h) {
    const int tid  = threadIdx.x;
    const int m    = tid & 15;
    const int q    = (tid >> 4) & 3;
    const int wave = tid >> 6;
    const int r0   = blockIdx.x * 16;
    const int c0   = wave * 32;

    const float*  xrow = x + (size_t)(r0 + m) * CH + q * 8;
    const ushort* w0   = wbf + (size_t)(c0 + m) * CH + q * 8;       // ct=0
    const ushort* w1   = w0 + 16 * CH;                              // ct=1

    f32x4 acc0 = {0.f, 0.f, 0.f, 0.f};
    f32x4 acc1 = {0.f, 0.f, 0.f, 0.f};

#pragma unroll
    for (int kc = 0; kc < CH; kc += 32) {
        float4 xa = *(const float4*)(xrow + kc);
        float4 xb = *(const float4*)(xrow + kc + 4);
        bf16x8 a;
        a[0] = (short)f2bf(xa.x); a[1] = (short)f2bf(xa.y);
        a[2] = (short)f2bf(xa.z); a[3] = (short)f2bf(xa.w);
        a[4] = (short)f2bf(xb.x); a[5] = (short)f2bf(xb.y);
        a[6] = (short)f2bf(xb.z); a[7] = (short)f2bf(xb.w);
        bf16x8 b0 = *(const bf16x8*)(w0 + kc);
        bf16x8 b1 = *(const bf16x8*)(w1 + kc);
        acc0 = __builtin_amdgcn_mfma_f32_16x16x32_bf16(a, b0, acc0, 0, 0, 0);
        acc1 = __builtin_amdgcn_mfma_f32_16x16x32_bf16(a, b1, acc1, 0, 0, 0);
    }

    const int col0 = c0 + m;
    const float bb0 = bias[col0];
    const float bb1 = bias[col0 + 16];
#pragma unroll
    for (int r = 0; r < 4; r++) {
        size_t row = (size_t)(r0 + q * 4 + r) * CH;
        h[row + col0]      = f2bf(acc0[r] + bb0);
        h[row + col0 + 16] = f2bf(acc1[r] + bb1);
    }
}

// ---------------- pass 1a: per-block bucket histogram ----------------
__global__ __launch_bounds__(256) void p1_count(const int* __restrict__ dst,
                                                int* __restrict__ counts) {
    __shared__ int cnt[NB];
    const int t = threadIdx.x, k = blockIdx.x;
    if (t < NB) cnt[t] = 0;
    __syncthreads();
    const int* dp = dst + k * EPB;
    for (int i = t; i < EPB; i += 256) atomicAdd(&cnt[dp[i] >> 8], 1);
    __syncthreads();
    if (t < NB) counts[t * PBLK + k] = cnt[t];   // bucket-major [NB][PBLK]
}

// ---------------- scan of 50176 (bucket,block) counts, in place ----------------
__global__ __launch_bounds__(1024) void scan_counts(int* __restrict__ counts,
                                                    int* __restrict__ base) {
    __shared__ int s[1024];
    const int t = threadIdx.x;           // chunk [t*49, t*49+49)
    int sum = 0;
    for (int i = 0; i < 49; i++) sum += counts[t * 49 + i];
    s[t] = sum;
    __syncthreads();
    for (int o = 1; o < 1024; o <<= 1) {
        int v = (t >= o) ? s[t - o] : 0;
        __syncthreads();
        s[t] += v;
        __syncthreads();
    }
    int run = s[t] - sum;                // exclusive prefix of chunk
    for (int i = 0; i < 49; i++) {
        int v = counts[t * 49 + i];
        counts[t * 49 + i] = run;
        run += v;
    }
    __syncthreads();
    if (t < NB)  base[t]  = counts[t * PBLK];   // bucket start
    if (t == NB) base[NB] = E;
}

// ---------------- pass 1b: write (dst,src) pairs to private slots ----------------
__global__ __launch_bounds__(256) void p1_write(const int* __restrict__ ei,
                                                const int* __restrict__ counts,
                                                int2* __restrict__ pairs) {
    __shared__ int cur[NB];
    const int t = threadIdx.x, k = blockIdx.x;
    if (t < NB) cur[t] = counts[t * PBLK + k];   // this block's private slot base
    __syncthreads();
    const int* dp = ei + k * EPB;
    const int* sp = ei + E + k * EPB;
    for (int i = t; i < EPB; i += 256) {
        int d = dp[i], s = sp[i];
        int p = atomicAdd(&cur[d >> 8], 1);      // LDS atomic, no contention issue
        pairs[p] = make_int2(d, s);
    }
}

// ---------------- pass 2: per-bucket local CSR build ----------------
__global__ __launch_bounds__(256) void p2_build(const int2* __restrict__ pairs,
                                                const int* __restrict__ base,
                                                int* __restrict__ deg,
                                                int* __restrict__ offs,
                                                int* __restrict__ csr) {
    __shared__ int hist[256], scn[256], cur[256];
    const int b = blockIdx.x, t = threadIdx.x;
    const int lo = base[b], cnt = base[b + 1] - lo;
    hist[t] = 0;
    __syncthreads();
    for (int i = t; i < cnt; i += 256) atomicAdd(&hist[pairs[lo + i].x & 255], 1);
    __syncthreads();
    scn[t] = hist[t];
    __syncthreads();
    for (int o = 1; o < 256; o <<= 1) {
        int v = (t >= o) ? scn[t - o] : 0;
        __syncthreads();
        scn[t] += v;
        __syncthreads();
    }
    const int excl = scn[t] - hist[t];
    cur[t] = excl;
    const int n = b * 256 + t;
    if (n < N) { deg[n] = hist[t]; offs[n] = lo + excl; }
    __syncthreads();
    for (int i = t; i < cnt; i += 256) {
        int2 pr = pairs[lo + i];
        int p = atomicAdd(&cur[pr.x & 255], 1);
        csr[lo + p] = pr.y;                      // bucket span ~32 KB: L2-local
    }
}

// ---------------- pull aggregation over bf16 h (1 wave / node) ----------------
__global__ __launch_bounds__(64) void agg_bf16(const ushort* __restrict__ h,
                                               const int* __restrict__ offs,
                                               const int* __restrict__ deg,
                                               const int* __restrict__ csr,
                                               float* __restrict__ out) {
    const int n  = blockIdx.x;
    const int c2 = threadIdx.x;          // channel pair 0..63
    const int st = offs[n];
    const int cnt = deg[n];
    float a0 = 0.f, a1 = 0.f;
    for (int i = 0; i < cnt; i++) {
        int s = csr[st + i];
        unsigned v = *(const unsigned*)(h + (size_t)s * CH + c2 * 2);
        a0 += __uint_as_float(v << 16);
        a1 += __uint_as_float(v & 0xffff0000u);
    }
    *(float2*)(out + (size_t)n * CH + c2 * 2) = make_float2(a0, a1);
}

// ---------------- fallback: direct atomic scatter ----------------
__global__ void atomic_agg(const ushort* __restrict__ h, const int* __restrict__ ei,
                           float* __restrict__ out) {
    int tid = blockIdx.x * blockDim.x + threadIdx.x;
    int e  = tid >> 5;
    int cg = (tid & 31) * 4;
    if (e < E) {
        int d = ei[e];
        int s = ei[E + e];
        ushort4 v = *(const ushort4*)(h + (size_t)s * CH + cg);
        float* o = out + (size_t)d * CH + cg;
        atomicAdd(o + 0, __uint_as_float((unsigned)v.x << 16));
        atomicAdd(o + 1, __uint_as_float((unsigned)v.y << 16));
        atomicAdd(o + 2, __uint_as_float((unsigned)v.z << 16));
        atomicAdd(o + 3, __uint_as_float((unsigned)v.w << 16));
    }
}

extern "C" void kernel_launch(void* const* d_in, const int* in_sizes, int n_in,
                              void* d_out, int out_size, void* d_ws, size_t ws_size,
                              hipStream_t stream) {
    const float* x  = (const float*)d_in[0];
    const int*   ei = (const int*)d_in[1];   // [2][E] int32: row0=dst, row1=src
    const float* W  = (const float*)d_in[2];
    const float* b  = (const float*)d_in[3];
    float* out = (float*)d_out;

    char* ws = (char*)d_ws;
    ushort* h   = (ushort*)(ws + H_OFF);
    ushort* wbf = (ushort*)(ws + WBF_OFF);

    convert_w<<<64, 256, 0, stream>>>(W, wbf);
    gemm_mfma<<<N / 16, 256, 0, stream>>>(x, wbf, b, h);

    if (ws_size >= REQUIRED) {
        int2* pairs  = (int2*)(ws + PAIRS_OFF);
        int*  csr    = (int*)(ws + CSR_OFF);
        int*  counts = (int*)(ws + CNT_OFF);
        int*  deg    = (int*)(ws + DEG_OFF);
        int*  offs   = (int*)(ws + OFFS_OFF);
        int*  base   = (int*)(ws + BASE_OFF);

        p1_count<<<PBLK, 256, 0, stream>>>(ei, counts);
        scan_counts<<<1, 1024, 0, stream>>>(counts, base);
        p1_write<<<PBLK, 256, 0, stream>>>(ei, counts, pairs);
        p2_build<<<NB, 256, 0, stream>>>(pairs, base, deg, offs, csr);
        agg_bf16<<<N, 64, 0, stream>>>(h, offs, deg, csr, out);
    } else if (ws_size >= FB_REQUIRED) {
        hipMemsetAsync(out, 0, (size_t)out_size * sizeof(float), stream);
        int total = E * 32;
        atomic_agg<<<(total + 255) / 256, 256, 0, stream>>>(h, ei, out);
    }
}